// Round 11
// baseline (111.801 us; speedup 1.0000x reference)
//
#include <hip/hip_runtime.h>
#include <math.h>

// GNLoss: 4-level pyramid, triplet + Gauss-Newton loss over 8192 sample points.
// R10: single fused kernel. Standalone gather passes hit an ~81us wall
// invariant to occupancy/depth/shape/residency (R5-R9), while the main kernel
// serves MORE scattered loads in <8us. So: embed the fa@ma and fb@ng gathers
// into the main kernel's proven loop (20 named loads per channel-pair iter),
// delete the gather pass and ft/fn intermediates, sort only by mb.

struct BL { int x0, x1, y0, y1; float wx, wy; };
struct LevelPtrs { const float* fa[4]; const float* fb[4]; const float* nz[4]; };

__device__ __forceinline__ float2 load2u(const float* p) { float2 v; __builtin_memcpy(&v, p, 8); return v; }
__device__ __forceinline__ float4 load4u(const float* p) { float4 v; __builtin_memcpy(&v, p, 16); return v; }

// Reparam clamp: if x0 lands on the last texel, shift to (W-2, wx=1).
// Reproduces reference clamp semantics exactly (x1=min(x0+1,W-1)) while
// guaranteeing x1 = x0+1 — every 2-texel row load is in-plane and branch-free.
__device__ __forceinline__ BL bl_setup2(float px, float py, int W, int H) {
    BL r;
    float x = fminf(fmaxf(px, 0.0f), (float)(W - 1));
    float y = fminf(fmaxf(py, 0.0f), (float)(H - 1));
    float fx = floorf(x), fy = floorf(y);
    r.wx = x - fx; r.wy = y - fy;
    r.x0 = (int)fx; r.y0 = (int)fy;
    if (r.x0 >= W - 1) { r.x0 = W - 2; r.wx = 1.0f; }
    if (r.y0 >= H - 1) { r.y0 = H - 2; r.wy = 1.0f; }
    r.x1 = r.x0 + 1;
    r.y1 = r.y0 + 1;
    return r;
}

__device__ __forceinline__ float bl_lerp(float2 r0, float2 r1, const BL& s) {
    float t0 = r0.x + s.wx * (r0.y - r0.x);
    float t1 = r1.x + s.wx * (r1.y - r1.x);
    return t0 + s.wy * (t1 - t0);
}

__device__ __forceinline__ float bl_eval_slow(const float* __restrict__ f, int W, const BL& s) {
    float v00 = f[s.y0 * W + s.x0];
    float v01 = f[s.y0 * W + s.x1];
    float v10 = f[s.y1 * W + s.x0];
    float v11 = f[s.y1 * W + s.x1];
    float a0 = v00 + s.wx * (v01 - v00);
    float a1 = v10 + s.wx * (v11 - v10);
    return a0 + s.wy * (a1 - a0);
}

__device__ __forceinline__ void j_eval_slow(const float* __restrict__ f, int W, int H,
                                            const BL& s, float& Jx, float& Jy) {
    int xR0 = min(s.x0 + 1, W - 1), xL0 = max(s.x0 - 1, 0);
    int xR1 = min(s.x1 + 1, W - 1), xL1 = max(s.x1 - 1, 0);
    int yD0 = min(s.y0 + 1, H - 1), yU0 = max(s.y0 - 1, 0);
    int yD1 = min(s.y1 + 1, H - 1), yU1 = max(s.y1 - 1, 0);
    const float* r0 = f + s.y0 * W;
    const float* r1 = f + s.y1 * W;
    float gx00 = r0[xR0] - r0[xL0];
    float gx01 = r0[xR1] - r0[xL1];
    float gx10 = r1[xR0] - r1[xL0];
    float gx11 = r1[xR1] - r1[xL1];
    float gy00 = f[yD0 * W + s.x0] - f[yU0 * W + s.x0];
    float gy01 = f[yD0 * W + s.x1] - f[yU0 * W + s.x1];
    float gy10 = f[yD1 * W + s.x0] - f[yU1 * W + s.x0];
    float gy11 = f[yD1 * W + s.x1] - f[yU1 * W + s.x1];
    float g0 = gx00 + s.wx * (gx01 - gx00);
    float g1 = gx10 + s.wx * (gx11 - gx10);
    Jx = 0.5f * (g0 + s.wy * (g1 - g0));
    float h0 = gy00 + s.wx * (gy01 - gy00);
    float h1 = gy10 + s.wx * (gy11 - gy10);
    Jy = 0.5f * (h0 + s.wy * (h1 - h0));
}

__device__ __forceinline__ float wave64_sum(float v) {
    v += __shfl_xor(v, 32);
    v += __shfl_xor(v, 16);
    v += __shfl_xor(v, 8);
    v += __shfl_xor(v, 4);
    v += __shfl_xor(v, 2);
    v += __shfl_xor(v, 1);
    return v;
}

__device__ __forceinline__ float warp32_sum(float v) {
    v += __shfl_xor(v, 16);
    v += __shfl_xor(v, 8);
    v += __shfl_xor(v, 4);
    v += __shfl_xor(v, 2);
    v += __shfl_xor(v, 1);
    return v;
}

// Morton-sort the 2048 points of one batch by mb. 4 blocks (one per batch).
__global__ __launch_bounds__(1024) void sort_mb_kernel(
    const float* __restrict__ mb, int* __restrict__ perm) {
    const int b = blockIdx.x;
    __shared__ unsigned int keys[2048];
    const float* cb = mb + (size_t)b * 2048 * 2;
    for (int i = threadIdx.x; i < 2048; i += 1024) {
        int ix = min(max((int)cb[i * 2 + 0], 0), 1023);
        int iy = min(max((int)cb[i * 2 + 1], 0), 1023);
        unsigned m = 0;
        #pragma unroll
        for (int t = 0; t < 10; ++t)
            m |= (((unsigned)(ix >> t) & 1u) << (2 * t)) | (((unsigned)(iy >> t) & 1u) << (2 * t + 1));
        keys[i] = (m << 11) | (unsigned)i;
    }
    __syncthreads();
    for (unsigned k = 2; k <= 2048; k <<= 1) {
        for (unsigned j = k >> 1; j > 0; j >>= 1) {
            unsigned t = threadIdx.x;
            unsigned i1 = 2 * t - (t & (j - 1));
            unsigned i2 = i1 + j;
            bool up = ((i1 & k) == 0);
            unsigned a = keys[i1], c = keys[i2];
            if ((a > c) == up) { keys[i1] = c; keys[i2] = a; }
            __syncthreads();
        }
    }
    for (int i = threadIdx.x; i < 2048; i += 1024)
        perm[b * 2048 + i] = (int)(keys[i] & 2047u);
}

// Accumulate one channel: fav/fpv/fnv branch-free lerps; fsv/J from the 4x4
// patch when interior, slow path otherwise.
__device__ __forceinline__ void consume_ch2(
    const float* __restrict__ plane, int W, int H,
    const BL& sa, const BL& sb, const BL& sg, const BL& sx, bool interior,
    float2 va0, float2 va1, float2 m0, float2 m1, float2 g0v, float2 g1v,
    float4 r0, float4 r1, float4 r2, float4 r3,
    float& sp, float& sn, float& aa, float& dd, float& bb, float& bx, float& by) {
    float fav = bl_lerp(va0, va1, sa);
    float fpv = bl_lerp(m0, m1, sb);
    float fnv = bl_lerp(g0v, g1v, sg);
    float fsv, Jx, Jy;
    if (interior) {
        float wx = sx.wx, wy = sx.wy;
        float a0 = r1.y + wx * (r1.z - r1.y);
        float a1 = r2.y + wx * (r2.z - r2.y);
        fsv = a0 + wy * (a1 - a0);
        float gx00 = r1.z - r1.x, gx01 = r1.w - r1.y;
        float gx10 = r2.z - r2.x, gx11 = r2.w - r2.y;
        float gy00 = r2.y - r0.y, gy01 = r2.z - r0.z;
        float gy10 = r3.y - r1.y, gy11 = r3.z - r1.z;
        float g0 = gx00 + wx * (gx01 - gx00);
        float g1 = gx10 + wx * (gx11 - gx10);
        Jx = 0.5f * (g0 + wy * (g1 - g0));
        float h0 = gy00 + wx * (gy01 - gy00);
        float h1 = gy10 + wx * (gy11 - gy10);
        Jy = 0.5f * (h0 + wy * (h1 - h0));
    } else {
        fsv = bl_eval_slow(plane, W, sx);
        j_eval_slow(plane, W, H, sx, Jx, Jy);
    }
    float rr = fsv - fav;
    float dp = fav - fpv, dn = fav - fnv;
    sp += dp * dp;
    sn += dn * dn;
    aa += Jx * Jx;
    dd += Jy * Jy;
    bb += Jx * Jy;
    bx += Jx * rr;
    by += Jy * rr;
}

// THE kernel: 512 blocks (lvl3 first); block = 4 waves x (64 points x 8 ch).
// Per channel-pair iteration: 20 named loads (fa@ma 2x2 ×2, fb@mb 2x2 ×2,
// fb@ng 2x2 ×2, fb@xs 4x4 ×2) then consume — the loop shape that serves
// scattered loads at ~10x the standalone-gather rate.
__global__ __launch_bounds__(256) void gn_fused_kernel(
    LevelPtrs P, const float* __restrict__ ma, const float* __restrict__ mb,
    const float* __restrict__ ng, const int* __restrict__ perm_mb,
    float* __restrict__ blk_out) {
    const int bid = blockIdx.x;
    const int lvl = 3 - (bid >> 7);
    const int g = bid & 127;
    const int tid = threadIdx.x;
    const int lane = tid & 63, w = tid >> 6, ch0 = w * 8;
    const int rank = g * 64 + lane;
    const int b = rank >> 11;
    const int q = (b << 11) + perm_mb[rank];
    const int H = 64 << lvl, W = H, HW = H * W;
    const float inv_s = 0.0625f * (float)(1 << lvl);
    const float* noise = P.nz[lvl];
    const int p2 = q * 2;
    const float nzx = noise[p2], nzy = noise[p2 + 1];
    const float pax = ma[p2] * inv_s, pay = ma[p2 + 1] * inv_s;
    const float pbx = mb[p2] * inv_s, pby = mb[p2 + 1] * inv_s;
    const float pnx = ng[p2] * inv_s, pny = ng[p2 + 1] * inv_s;
    const float xsx = nzx + pbx, xsy = nzy + pby;
    BL sa = bl_setup2(pax, pay, W, H);
    BL sb = bl_setup2(pbx, pby, W, H);
    BL sg = bl_setup2(pnx, pny, W, H);
    BL sx = bl_setup2(xsx, xsy, W, H);
    const bool interior = (sx.x0 >= 1) & (sx.x0 <= W - 3) & (sx.y0 >= 1) & (sx.y0 <= H - 3);
    const int pbx0 = min(max(sx.x0 - 1, 0), W - 4);
    const int pby0 = min(max(sx.y0 - 1, 0), H - 4);
    const float* fa0 = P.fa[lvl] + (size_t)(b * 32 + ch0) * HW;
    const float* fb0 = P.fb[lvl] + (size_t)(b * 32 + ch0) * HW;
    const int maoff = sa.y0 * W + sa.x0;
    const int mboff = sb.y0 * W + sb.x0;
    const int ngoff = sg.y0 * W + sg.x0;
    const int pboff = pby0 * W + pbx0;

    float sp = 0, sn = 0, aa = 0, dd = 0, bb = 0, bx = 0, by = 0;
    #pragma unroll
    for (int cc = 0; cc < 8; cc += 2) {
        const float* a0p = fa0 + (size_t)cc * HW;
        const float* a1p = a0p + HW;
        const float* b0p = fb0 + (size_t)cc * HW;
        const float* b1p = b0p + HW;
        // ---- 20 named loads, issued ahead of consumption ----
        float2 va00 = load2u(a0p + maoff);
        float2 va01 = load2u(a0p + maoff + W);
        float2 va10 = load2u(a1p + maoff);
        float2 va11 = load2u(a1p + maoff + W);
        float2 m00 = load2u(b0p + mboff);
        float2 m01 = load2u(b0p + mboff + W);
        float2 m10 = load2u(b1p + mboff);
        float2 m11 = load2u(b1p + mboff + W);
        float2 g00 = load2u(b0p + ngoff);
        float2 g01 = load2u(b0p + ngoff + W);
        float2 g10 = load2u(b1p + ngoff);
        float2 g11 = load2u(b1p + ngoff + W);
        const float* xb0 = b0p + pboff;
        const float* xb1 = b1p + pboff;
        float4 r00 = load4u(xb0), r01 = load4u(xb0 + W), r02 = load4u(xb0 + 2 * W), r03 = load4u(xb0 + 3 * W);
        float4 r10 = load4u(xb1), r11 = load4u(xb1 + W), r12 = load4u(xb1 + 2 * W), r13 = load4u(xb1 + 3 * W);
        // ---- consume ----
        consume_ch2(b0p, W, H, sa, sb, sg, sx, interior,
                    va00, va01, m00, m01, g00, g01, r00, r01, r02, r03,
                    sp, sn, aa, dd, bb, bx, by);
        consume_ch2(b1p, W, H, sa, sb, sg, sx, interior,
                    va10, va11, m10, m11, g10, g11, r10, r11, r12, r13,
                    sp, sn, aa, dd, bb, bx, by);
    }

    __shared__ float red[4][64][7];
    red[w][lane][0] = sp; red[w][lane][1] = sn; red[w][lane][2] = aa;
    red[w][lane][3] = dd; red[w][lane][4] = bb; red[w][lane][5] = bx;
    red[w][lane][6] = by;
    __syncthreads();
    if (tid < 64) {
        float t[7];
        #pragma unroll
        for (int k = 0; k < 7; ++k)
            t[k] = red[0][tid][k] + red[1][tid][k] + red[2][tid][k] + red[3][tid][k];
        float a2 = t[2] + 1e-9f, d2 = t[3] + 1e-9f, b2 = t[4];
        float det = a2 * d2 - b2 * b2;
        float ix = (d2 * t[5] - b2 * t[6]) / det;
        float iy = (a2 * t[6] - b2 * t[5]) / det;
        // du = ub - miu = i - noise (noise of THIS tid's point)
        const int rank2 = g * 64 + tid;
        const int b2i = rank2 >> 11;
        const int q2 = (b2i << 11) + perm_mb[rank2];
        const float nz2x = noise[q2 * 2], nz2y = noise[q2 * 2 + 1];
        float dux = ix - nz2x;
        float duy = iy - nz2y;
        float qv = a2 * dux * dux + 2.0f * b2 * dux * duy + d2 * duy * duy;
        float trip = fmaxf(sqrtf(t[0]) - sqrtf(t[1]) + 1.0f, 0.0f);
        float ld = logf(det);
        trip = wave64_sum(trip);
        qv = wave64_sum(qv);
        ld = wave64_sum(ld);
        if (tid == 0) {
            blk_out[bid * 3 + 0] = trip;
            blk_out[bid * 3 + 1] = qv;
            blk_out[bid * 3 + 2] = ld;
        }
    }
}

__global__ __launch_bounds__(256) void gn_final_kernel(
    const float* __restrict__ part, int nblk, float* __restrict__ out) {
    __shared__ double sd[3][256];
    double st = 0.0, sq = 0.0, sl = 0.0;
    for (int i = threadIdx.x; i < nblk; i += 256) {
        st += (double)part[i * 3 + 0];
        sq += (double)part[i * 3 + 1];
        sl += (double)part[i * 3 + 2];
    }
    sd[0][threadIdx.x] = st; sd[1][threadIdx.x] = sq; sd[2][threadIdx.x] = sl;
    __syncthreads();
    for (int s = 128; s > 0; s >>= 1) {
        if (threadIdx.x < s) {
            sd[0][threadIdx.x] += sd[0][threadIdx.x + s];
            sd[1][threadIdx.x] += sd[1][threadIdx.x + s];
            sd[2][threadIdx.x] += sd[2][threadIdx.x + s];
        }
        __syncthreads();
    }
    if (threadIdx.x == 0) {
        double S_t = sd[0][0], S_q = sd[1][0], S_l = sd[2][0];
        double tl = 100.0 * S_t / 8192.0;                           // CONTR_LAMDA * sum(mean)
        double e2 = 4.0 * 8192.0 * 1.8378770664093453 - 0.5 * S_l;  // sum_i B*N*ln(2pi) - 0.5*sum(logdet)
        double gl = 0.3 * (0.5 * S_q + (2.0 / 7.0) * e2);           // GN_LAMDA * sum(e1 + 2*e2/7)
        out[0] = (float)(tl + gl);
        out[1] = (float)tl;
        out[2] = (float)gl;
    }
}

// ---------------- R4 fallback path (used only if ws is too small) ----------
struct Task {
    const float* fac;
    const float* fbc;
    BL sa, sb, sg, sx;
    float nzx, nzy;
    bool fast;
    float2 va0, va1, vb0, vb1, vg0, vg1;
    float4 xm, x0, x1, x2;
    float fav, fpv, fnv, fsv, Jx, Jy;
};

__device__ __forceinline__ void task_setup(Task& T, int rank, const LevelPtrs& P,
                                           int lvl, int c, int W, int H, float inv_s,
                                           const float* __restrict__ ma,
                                           const float* __restrict__ mb,
                                           const float* __restrict__ ng) {
    const int b = rank >> 11;
    const int q = rank;
    const int HW = H * W;
    T.fac = P.fa[lvl] + (size_t)(b * 32 + c) * HW;
    T.fbc = P.fb[lvl] + (size_t)(b * 32 + c) * HW;
    const float* noise = P.nz[lvl];
    const int p2 = q * 2;
    T.nzx = noise[p2]; T.nzy = noise[p2 + 1];
    const float pax = ma[p2] * inv_s, pay = ma[p2 + 1] * inv_s;
    const float pbx = mb[p2] * inv_s, pby = mb[p2 + 1] * inv_s;
    const float pnx = ng[p2] * inv_s, pny = ng[p2 + 1] * inv_s;
    const float xsx = T.nzx + pbx, xsy = T.nzy + pby;
    T.sa = bl_setup2(pax, pay, W, H);
    T.sb = bl_setup2(pbx, pby, W, H);
    T.sg = bl_setup2(pnx, pny, W, H);
    T.sx = bl_setup2(xsx, xsy, W, H);
    T.fast = (T.sx.x0 >= 1) & (T.sx.x0 <= W - 3) & (T.sx.y0 >= 1) & (T.sx.y0 <= H - 3);
}

__device__ __forceinline__ void task_issue(Task& T, int W, int H) {
    T.va0 = load2u(T.fac + T.sa.y0 * W + T.sa.x0);
    T.va1 = load2u(T.fac + T.sa.y1 * W + T.sa.x0);
    T.vb0 = load2u(T.fbc + T.sb.y0 * W + T.sb.x0);
    T.vb1 = load2u(T.fbc + T.sb.y1 * W + T.sb.x0);
    T.vg0 = load2u(T.fbc + T.sg.y0 * W + T.sg.x0);
    T.vg1 = load2u(T.fbc + T.sg.y1 * W + T.sg.x0);
    int bx0 = min(max(T.sx.x0 - 1, 0), W - 4);
    int by0 = min(max(T.sx.y0 - 1, 0), H - 4);
    const float* xbp = T.fbc + by0 * W + bx0;
    T.xm = load4u(xbp);
    T.x0 = load4u(xbp + W);
    T.x1 = load4u(xbp + 2 * W);
    T.x2 = load4u(xbp + 3 * W);
}

__device__ __forceinline__ void task_consume(Task& T, int W, int H) {
    {
        float t0 = T.va0.x + T.sa.wx * (T.va0.y - T.va0.x);
        float t1 = T.va1.x + T.sa.wx * (T.va1.y - T.va1.x);
        T.fav = t0 + T.sa.wy * (t1 - t0);
    }
    {
        float t0 = T.vb0.x + T.sb.wx * (T.vb0.y - T.vb0.x);
        float t1 = T.vb1.x + T.sb.wx * (T.vb1.y - T.vb1.x);
        T.fpv = t0 + T.sb.wy * (t1 - t0);
    }
    {
        float t0 = T.vg0.x + T.sg.wx * (T.vg0.y - T.vg0.x);
        float t1 = T.vg1.x + T.sg.wx * (T.vg1.y - T.vg1.x);
        T.fnv = t0 + T.sg.wy * (t1 - t0);
    }
    if (T.fast) {
        float wx = T.sx.wx, wy = T.sx.wy;
        float t0 = T.x0.y + wx * (T.x0.z - T.x0.y);
        float t1 = T.x1.y + wx * (T.x1.z - T.x1.y);
        T.fsv = t0 + wy * (t1 - t0);
        float gx00 = T.x0.z - T.x0.x, gx01 = T.x0.w - T.x0.y;
        float gx10 = T.x1.z - T.x1.x, gx11 = T.x1.w - T.x1.y;
        float gy00 = T.x1.y - T.xm.y, gy01 = T.x1.z - T.xm.z;
        float gy10 = T.x2.y - T.x0.y, gy11 = T.x2.z - T.x0.z;
        float g0 = gx00 + wx * (gx01 - gx00);
        float g1 = gx10 + wx * (gx11 - gx10);
        T.Jx = 0.5f * (g0 + wy * (g1 - g0));
        float h0 = gy00 + wx * (gy01 - gy00);
        float h1 = gy10 + wx * (gy11 - gy10);
        T.Jy = 0.5f * (h0 + wy * (h1 - h0));
    } else {
        T.fsv = bl_eval_slow(T.fbc, W, T.sx);
        j_eval_slow(T.fbc, W, H, T.sx, T.Jx, T.Jy);
    }
}

__device__ __forceinline__ void task_reduce(const Task& T, int c, float* red0,
                                            float* red1, float* red2, int slot2) {
    float r = T.fsv - T.fav;
    float a  = warp32_sum(T.Jx * T.Jx);
    float dd = warp32_sum(T.Jy * T.Jy);
    float bb = warp32_sum(T.Jx * T.Jy);
    float bx = warp32_sum(T.Jx * r);
    float by = warp32_sum(T.Jy * r);
    float dfp = T.fav - T.fpv, dfn = T.fav - T.fnv;
    float sp = warp32_sum(dfp * dfp);
    float sn = warp32_sum(dfn * dfn);
    if (c == 0) {
        a += 1e-9f; dd += 1e-9f;
        float det = a * dd - bb * bb;
        float ix = (dd * bx - bb * by) / det;
        float iy = (a * by - bb * bx) / det;
        float dux = ix - T.nzx;
        float duy = iy - T.nzy;
        float qv = a * dux * dux + 2.0f * bb * dux * duy + dd * duy * duy;
        red0[slot2] = fmaxf(sqrtf(sp) - sqrtf(sn) + 1.0f, 0.0f);
        red1[slot2] = qv;
        red2[slot2] = logf(det);
    }
}

__global__ __launch_bounds__(256) void gn_fallback_kernel(
    LevelPtrs P, const float* __restrict__ ma, const float* __restrict__ mb,
    const float* __restrict__ ng, float* __restrict__ blk_out) {
    const int tid = threadIdx.x;
    const int c = tid & 31;
    const int slot = tid >> 5;
    const int lvl = slot >> 1;
    const int po = slot & 1;
    const int bid = blockIdx.x;
    const int base = bid * 4;
    const int H = 64 << lvl;
    const int W = H;
    const float inv_s = 0.0625f * (float)(1 << lvl);

    Task T0, T1;
    task_setup(T0, base + po,     P, lvl, c, W, H, inv_s, ma, mb, ng);
    task_setup(T1, base + 2 + po, P, lvl, c, W, H, inv_s, ma, mb, ng);
    task_issue(T0, W, H);
    task_issue(T1, W, H);
    task_consume(T0, W, H);
    task_consume(T1, W, H);

    __shared__ float red[3][16];
    task_reduce(T0, c, red[0], red[1], red[2], slot * 2 + 0);
    task_reduce(T1, c, red[0], red[1], red[2], slot * 2 + 1);
    __syncthreads();
    if (tid == 0) {
        float t = 0.0f, qq = 0.0f, l = 0.0f;
        #pragma unroll
        for (int i = 0; i < 16; ++i) { t += red[0][i]; qq += red[1][i]; l += red[2][i]; }
        blk_out[bid * 3 + 0] = t;
        blk_out[bid * 3 + 1] = qq;
        blk_out[bid * 3 + 2] = l;
    }
}

extern "C" void kernel_launch(void* const* d_in, const int* in_sizes, int n_in,
                              void* d_out, int out_size, void* d_ws, size_t ws_size,
                              hipStream_t stream) {
    // setup_inputs() dict order: fa0,fb0,noise0, ..., ma,mb,neg,epoch.
    const bool dict_order = (in_sizes[1] == in_sizes[0]);
    LevelPtrs P;
    for (int i = 0; i < 4; ++i) {
        if (dict_order) {
            P.fa[i] = (const float*)d_in[3 * i + 0];
            P.fb[i] = (const float*)d_in[3 * i + 1];
            P.nz[i] = (const float*)d_in[3 * i + 2];
        } else {
            P.fa[i] = (const float*)d_in[i];
            P.fb[i] = (const float*)d_in[4 + i];
            P.nz[i] = (const float*)d_in[8 + i];
        }
    }
    const float* ma = (const float*)d_in[12];
    const float* mb = (const float*)d_in[13];
    const float* ng = (const float*)d_in[14];

    float* ws = (float*)d_ws;
    // ws layout (floats): [0,1536) partials (512x3) | [1536, +8192) perm_mb ints
    const size_t NEED = (1536 + 8192) * 4;

    if (ws_size >= NEED) {
        float* partials = ws;
        int* perm = (int*)(ws + 1536);
        sort_mb_kernel<<<4, 1024, 0, stream>>>(mb, perm);
        gn_fused_kernel<<<512, 256, 0, stream>>>(P, ma, mb, ng, perm, partials);
        gn_final_kernel<<<1, 256, 0, stream>>>(partials, 512, (float*)d_out);
    } else {
        // Fallback: R4-style fused kernel (no sort).
        float* partials = ws;                // 2048 blocks x 3 floats = 24 KB
        gn_fallback_kernel<<<2048, 256, 0, stream>>>(P, ma, mb, ng, partials);
        gn_final_kernel<<<1, 256, 0, stream>>>(partials, 2048, (float*)d_out);
    }
}

// Round 12
// 88.847 us; speedup vs baseline: 1.2583x; 1.2583x over previous
//
#include <hip/hip_runtime.h>
#include <math.h>

// GNLoss: 4-level pyramid, triplet + Gauss-Newton loss over 8192 sample points.
// R11: revert to the best split structure (R5, 90.7us) + switch point sort from
// Morton to ROW-MAJOR (y<<10|x). Model: gather eats a compulsory ~107MB cold
// HBM fetch each replay at the scattered-line DRAM efficiency (1.3 TB/s with
// Morton order). Row-major order makes consecutive points share image rows =
// consecutive addresses = DRAM row-buffer hits -> higher cold-fetch efficiency.

struct BL { int x0, x1, y0, y1; float wx, wy; };
struct LevelPtrs { const float* fa[4]; const float* fb[4]; const float* nz[4]; };

__device__ __forceinline__ float2 load2u(const float* p) { float2 v; __builtin_memcpy(&v, p, 8); return v; }
__device__ __forceinline__ float4 load4u(const float* p) { float4 v; __builtin_memcpy(&v, p, 16); return v; }

// Reparam clamp: if x0 lands on the last texel, shift to (W-2, wx=1).
// Reproduces reference clamp semantics exactly (x1=min(x0+1,W-1)) while
// guaranteeing x1 = x0+1 — every 2-texel row load is in-plane and branch-free.
__device__ __forceinline__ BL bl_setup2(float px, float py, int W, int H) {
    BL r;
    float x = fminf(fmaxf(px, 0.0f), (float)(W - 1));
    float y = fminf(fmaxf(py, 0.0f), (float)(H - 1));
    float fx = floorf(x), fy = floorf(y);
    r.wx = x - fx; r.wy = y - fy;
    r.x0 = (int)fx; r.y0 = (int)fy;
    if (r.x0 >= W - 1) { r.x0 = W - 2; r.wx = 1.0f; }
    if (r.y0 >= H - 1) { r.y0 = H - 2; r.wy = 1.0f; }
    r.x1 = r.x0 + 1;
    r.y1 = r.y0 + 1;
    return r;
}

__device__ __forceinline__ float bl_eval_slow(const float* __restrict__ f, int W, const BL& s) {
    float v00 = f[s.y0 * W + s.x0];
    float v01 = f[s.y0 * W + s.x1];
    float v10 = f[s.y1 * W + s.x0];
    float v11 = f[s.y1 * W + s.x1];
    float a0 = v00 + s.wx * (v01 - v00);
    float a1 = v10 + s.wx * (v11 - v10);
    return a0 + s.wy * (a1 - a0);
}

__device__ __forceinline__ void j_eval_slow(const float* __restrict__ f, int W, int H,
                                            const BL& s, float& Jx, float& Jy) {
    int xR0 = min(s.x0 + 1, W - 1), xL0 = max(s.x0 - 1, 0);
    int xR1 = min(s.x1 + 1, W - 1), xL1 = max(s.x1 - 1, 0);
    int yD0 = min(s.y0 + 1, H - 1), yU0 = max(s.y0 - 1, 0);
    int yD1 = min(s.y1 + 1, H - 1), yU1 = max(s.y1 - 1, 0);
    const float* r0 = f + s.y0 * W;
    const float* r1 = f + s.y1 * W;
    float gx00 = r0[xR0] - r0[xL0];
    float gx01 = r0[xR1] - r0[xL1];
    float gx10 = r1[xR0] - r1[xL0];
    float gx11 = r1[xR1] - r1[xL1];
    float gy00 = f[yD0 * W + s.x0] - f[yU0 * W + s.x0];
    float gy01 = f[yD0 * W + s.x1] - f[yU0 * W + s.x1];
    float gy10 = f[yD1 * W + s.x0] - f[yU1 * W + s.x0];
    float gy11 = f[yD1 * W + s.x1] - f[yU1 * W + s.x1];
    float g0 = gx00 + s.wx * (gx01 - gx00);
    float g1 = gx10 + s.wx * (gx11 - gx10);
    Jx = 0.5f * (g0 + s.wy * (g1 - g0));
    float h0 = gy00 + s.wx * (gy01 - gy00);
    float h1 = gy10 + s.wx * (gy11 - gy10);
    Jy = 0.5f * (h0 + s.wy * (h1 - h0));
}

__device__ __forceinline__ float wave64_sum(float v) {
    v += __shfl_xor(v, 32);
    v += __shfl_xor(v, 16);
    v += __shfl_xor(v, 8);
    v += __shfl_xor(v, 4);
    v += __shfl_xor(v, 2);
    v += __shfl_xor(v, 1);
    return v;
}

__device__ __forceinline__ float warp32_sum(float v) {
    v += __shfl_xor(v, 16);
    v += __shfl_xor(v, 8);
    v += __shfl_xor(v, 4);
    v += __shfl_xor(v, 2);
    v += __shfl_xor(v, 1);
    return v;
}

// Sort the 2048 points of one batch by ROW-MAJOR key (y<<10 | x) of one coord
// array. 12 blocks: cid = bid>>2 selects {ma, mb, ng}; b = bid&3.
// Row-major (not Morton): consecutive sorted points share image rows ->
// consecutive line addresses -> DRAM row-buffer hits on the cold fetch.
__global__ __launch_bounds__(1024) void sort3_kernel(
    const float* __restrict__ ma, const float* __restrict__ mb,
    const float* __restrict__ ng, int* __restrict__ perm) {
    const int cid = blockIdx.x >> 2;
    const int b = blockIdx.x & 3;
    const float* coords = (cid == 0) ? ma : (cid == 1) ? mb : ng;
    __shared__ unsigned int keys[2048];
    const float* cb = coords + (size_t)b * 2048 * 2;
    for (int i = threadIdx.x; i < 2048; i += 1024) {
        int ix = min(max((int)cb[i * 2 + 0], 0), 1023);
        int iy = min(max((int)cb[i * 2 + 1], 0), 1023);
        unsigned m = ((unsigned)iy << 10) | (unsigned)ix;   // row-major key
        keys[i] = (m << 11) | (unsigned)i;                  // 20b key + 11b idx
    }
    __syncthreads();
    for (unsigned k = 2; k <= 2048; k <<= 1) {
        for (unsigned j = k >> 1; j > 0; j >>= 1) {
            unsigned t = threadIdx.x;
            unsigned i1 = 2 * t - (t & (j - 1));
            unsigned i2 = i1 + j;
            bool up = ((i1 & k) == 0);
            unsigned a = keys[i1], c = keys[i2];
            if ((a > c) == up) { keys[i1] = c; keys[i2] = a; }
            __syncthreads();
        }
    }
    for (int i = threadIdx.x; i < 2048; i += 1024)
        perm[cid * 8192 + b * 2048 + i] = (int)(keys[i] & 2047u);
}

// Pass 1+2: gather f_t = fa@ma (role 0, ma-sorted) and fn = fb@ng (role 1,
// ng-sorted) into per-(pt,ch) arrays. 1024 blocks; role = bid&1, lvl3 first.
// Block = 4 waves x (64 points x 8 channels).
__global__ __launch_bounds__(256) void gather_pass_kernel(
    LevelPtrs P, const float* __restrict__ ma, const float* __restrict__ ng,
    const int* __restrict__ perm, float* __restrict__ ft, float* __restrict__ fn) {
    const int bid = blockIdx.x;
    const int role = bid & 1;               // 0: ft (fa@ma), 1: fn (fb@ng)
    const int r = bid >> 1;                 // 0..511
    const int lvl = 3 - (r >> 7);           // lvl3 blocks dispatched first
    const int g = r & 127;
    const int tid = threadIdx.x;
    const int lane = tid & 63, w = tid >> 6, ch0 = w * 8;
    const int rank = g * 64 + lane;
    const int b = rank >> 11;
    const int* pm = perm + (role ? 2 * 8192 : 0);   // perm_ma or perm_ng
    const int q = (b << 11) + pm[rank];
    const int H = 64 << lvl, W = H, HW = H * W;
    const float inv_s = 0.0625f * (float)(1 << lvl);
    const float* coords = role ? ng : ma;
    const float px = coords[q * 2] * inv_s, py = coords[q * 2 + 1] * inv_s;
    BL s = bl_setup2(px, py, W, H);
    const float* src = role ? P.fb[lvl] : P.fa[lvl];
    const float* base = src + (size_t)(b * 32 + ch0) * HW + s.y0 * W + s.x0;

    float2 v0[8], v1[8];
    #pragma unroll
    for (int cc = 0; cc < 8; ++cc) {
        v0[cc] = load2u(base + (size_t)cc * HW);
        v1[cc] = load2u(base + (size_t)cc * HW + W);
    }
    float out[8];
    #pragma unroll
    for (int cc = 0; cc < 8; ++cc) {
        float t0 = v0[cc].x + s.wx * (v0[cc].y - v0[cc].x);
        float t1 = v1[cc].x + s.wx * (v1[cc].y - v1[cc].x);
        out[cc] = t0 + s.wy * (t1 - t0);
    }
    float* dst = (role ? fn : ft) + ((size_t)lvl * 8192 + q) * 32 + ch0;
    float4 o0 = {out[0], out[1], out[2], out[3]};
    float4 o1 = {out[4], out[5], out[6], out[7]};
    *(float4*)dst = o0;
    *(float4*)(dst + 4) = o1;
}

// Accumulate one channel's contribution to the 7 per-point sums.
__device__ __forceinline__ void consume_ch(
    const float* __restrict__ plane, int W, int H, const BL& sb, const BL& sx,
    bool interior, float2 m0, float2 m1,
    float4 r0, float4 r1, float4 r2, float4 r3,
    float ftv, float fnv,
    float& sp, float& sn, float& aa, float& dd, float& bb, float& bx, float& by) {
    float t0 = m0.x + sb.wx * (m0.y - m0.x);
    float t1 = m1.x + sb.wx * (m1.y - m1.x);
    float fpv = t0 + sb.wy * (t1 - t0);
    float fsv, Jx, Jy;
    if (interior) {
        float wx = sx.wx, wy = sx.wy;
        float a0 = r1.y + wx * (r1.z - r1.y);
        float a1 = r2.y + wx * (r2.z - r2.y);
        fsv = a0 + wy * (a1 - a0);
        float gx00 = r1.z - r1.x, gx01 = r1.w - r1.y;
        float gx10 = r2.z - r2.x, gx11 = r2.w - r2.y;
        float gy00 = r2.y - r0.y, gy01 = r2.z - r0.z;
        float gy10 = r3.y - r1.y, gy11 = r3.z - r1.z;
        float g0 = gx00 + wx * (gx01 - gx00);
        float g1 = gx10 + wx * (gx11 - gx10);
        Jx = 0.5f * (g0 + wy * (g1 - g0));
        float h0 = gy00 + wx * (gy01 - gy00);
        float h1 = gy10 + wx * (gy11 - gy10);
        Jy = 0.5f * (h0 + wy * (h1 - h0));
    } else {
        fsv = bl_eval_slow(plane, W, sx);
        j_eval_slow(plane, W, H, sx, Jx, Jy);
    }
    float rr = fsv - ftv;
    float dp = ftv - fpv, dn = ftv - fnv;
    sp += dp * dp;
    sn += dn * dn;
    aa += Jx * Jx;
    dd += Jy * Jy;
    bb += Jx * Jy;
    bx += Jx * rr;
    by += Jy * rr;
}

// Pass 3: mb-sorted main pass. 512 blocks (lvl3 first); block = 4 waves x
// (64 points x 8 channels). Gathers fb@mb + 4x4 xs patch; reads ft/fn
// coalesced; LDS-reduces 4 channel-groups; wave0 does per-point 2x2 solve.
__global__ __launch_bounds__(256) void gn_main_kernel(
    LevelPtrs P, const float* __restrict__ mb, const int* __restrict__ perm_mb,
    const float* __restrict__ ft, const float* __restrict__ fn,
    float* __restrict__ blk_out) {
    const int bid = blockIdx.x;
    const int lvl = 3 - (bid >> 7);
    const int g = bid & 127;
    const int tid = threadIdx.x;
    const int lane = tid & 63, w = tid >> 6, ch0 = w * 8;
    const int rank = g * 64 + lane;
    const int b = rank >> 11;
    const int q = (b << 11) + perm_mb[rank];
    const int H = 64 << lvl, W = H, HW = H * W;
    const float inv_s = 0.0625f * (float)(1 << lvl);
    const float* noise = P.nz[lvl];
    const int p2 = q * 2;
    const float nzx = noise[p2], nzy = noise[p2 + 1];
    const float pbx = mb[p2] * inv_s, pby = mb[p2 + 1] * inv_s;
    const float xsx = nzx + pbx, xsy = nzy + pby;
    BL sb = bl_setup2(pbx, pby, W, H);
    BL sx = bl_setup2(xsx, xsy, W, H);
    const bool interior = (sx.x0 >= 1) & (sx.x0 <= W - 3) & (sx.y0 >= 1) & (sx.y0 <= H - 3);
    // Clamped patch base: valid 4x4 block for every lane (garbage unused when !interior).
    const int pbx0 = min(max(sx.x0 - 1, 0), W - 4);
    const int pby0 = min(max(sx.y0 - 1, 0), H - 4);
    const float* fb0 = P.fb[lvl] + (size_t)(b * 32 + ch0) * HW;

    const float* ftp = ft + ((size_t)lvl * 8192 + q) * 32 + ch0;
    const float* fnp = fn + ((size_t)lvl * 8192 + q) * 32 + ch0;
    float4 ftA = *(const float4*)ftp, ftB = *(const float4*)(ftp + 4);
    float4 fnA = *(const float4*)fnp, fnB = *(const float4*)(fnp + 4);
    float ftv[8] = {ftA.x, ftA.y, ftA.z, ftA.w, ftB.x, ftB.y, ftB.z, ftB.w};
    float fnv[8] = {fnA.x, fnA.y, fnA.z, fnA.w, fnB.x, fnB.y, fnB.z, fnB.w};

    float sp = 0, sn = 0, aa = 0, dd = 0, bb = 0, bx = 0, by = 0;
    const int mboff0 = sb.y0 * W + sb.x0;
    const int pboff = pby0 * W + pbx0;
    #pragma unroll
    for (int cc = 0; cc < 8; cc += 2) {
        const float* p0 = fb0 + (size_t)cc * HW;
        const float* p1 = p0 + HW;
        float2 m00 = load2u(p0 + mboff0);
        float2 m01 = load2u(p0 + mboff0 + W);
        float2 m10 = load2u(p1 + mboff0);
        float2 m11 = load2u(p1 + mboff0 + W);
        const float* xb0 = p0 + pboff;
        const float* xb1 = p1 + pboff;
        float4 r00 = load4u(xb0), r01 = load4u(xb0 + W), r02 = load4u(xb0 + 2 * W), r03 = load4u(xb0 + 3 * W);
        float4 r10 = load4u(xb1), r11 = load4u(xb1 + W), r12 = load4u(xb1 + 2 * W), r13 = load4u(xb1 + 3 * W);
        consume_ch(p0, W, H, sb, sx, interior, m00, m01, r00, r01, r02, r03,
                   ftv[cc], fnv[cc], sp, sn, aa, dd, bb, bx, by);
        consume_ch(p1, W, H, sb, sx, interior, m10, m11, r10, r11, r12, r13,
                   ftv[cc + 1], fnv[cc + 1], sp, sn, aa, dd, bb, bx, by);
    }

    __shared__ float red[4][64][7];
    red[w][lane][0] = sp; red[w][lane][1] = sn; red[w][lane][2] = aa;
    red[w][lane][3] = dd; red[w][lane][4] = bb; red[w][lane][5] = bx;
    red[w][lane][6] = by;
    __syncthreads();
    if (tid < 64) {
        float t[7];
        #pragma unroll
        for (int k = 0; k < 7; ++k)
            t[k] = red[0][tid][k] + red[1][tid][k] + red[2][tid][k] + red[3][tid][k];
        float a2 = t[2] + 1e-9f, d2 = t[3] + 1e-9f, b2 = t[4];
        float det = a2 * d2 - b2 * b2;
        float ix = (d2 * t[5] - b2 * t[6]) / det;
        float iy = (a2 * t[6] - b2 * t[5]) / det;
        // du = ub - miu = i - noise (noise of THIS tid's point)
        const int rank2 = g * 64 + tid;
        const int b2i = rank2 >> 11;
        const int q2 = (b2i << 11) + perm_mb[rank2];
        const float nz2x = noise[q2 * 2], nz2y = noise[q2 * 2 + 1];
        float dux = ix - nz2x;
        float duy = iy - nz2y;
        float qv = a2 * dux * dux + 2.0f * b2 * dux * duy + d2 * duy * duy;
        float trip = fmaxf(sqrtf(t[0]) - sqrtf(t[1]) + 1.0f, 0.0f);
        float ld = logf(det);
        trip = wave64_sum(trip);
        qv = wave64_sum(qv);
        ld = wave64_sum(ld);
        if (tid == 0) {
            blk_out[bid * 3 + 0] = trip;
            blk_out[bid * 3 + 1] = qv;
            blk_out[bid * 3 + 2] = ld;
        }
    }
}

__global__ __launch_bounds__(256) void gn_final_kernel(
    const float* __restrict__ part, int nblk, float* __restrict__ out) {
    __shared__ double sd[3][256];
    double st = 0.0, sq = 0.0, sl = 0.0;
    for (int i = threadIdx.x; i < nblk; i += 256) {
        st += (double)part[i * 3 + 0];
        sq += (double)part[i * 3 + 1];
        sl += (double)part[i * 3 + 2];
    }
    sd[0][threadIdx.x] = st; sd[1][threadIdx.x] = sq; sd[2][threadIdx.x] = sl;
    __syncthreads();
    for (int s = 128; s > 0; s >>= 1) {
        if (threadIdx.x < s) {
            sd[0][threadIdx.x] += sd[0][threadIdx.x + s];
            sd[1][threadIdx.x] += sd[1][threadIdx.x + s];
            sd[2][threadIdx.x] += sd[2][threadIdx.x + s];
        }
        __syncthreads();
    }
    if (threadIdx.x == 0) {
        double S_t = sd[0][0], S_q = sd[1][0], S_l = sd[2][0];
        double tl = 100.0 * S_t / 8192.0;                           // CONTR_LAMDA * sum(mean)
        double e2 = 4.0 * 8192.0 * 1.8378770664093453 - 0.5 * S_l;  // sum_i B*N*ln(2pi) - 0.5*sum(logdet)
        double gl = 0.3 * (0.5 * S_q + (2.0 / 7.0) * e2);           // GN_LAMDA * sum(e1 + 2*e2/7)
        out[0] = (float)(tl + gl);
        out[1] = (float)tl;
        out[2] = (float)gl;
    }
}

// ---------------- Fallback path (used only if ws is too small) ----------
struct Task {
    const float* fac;
    const float* fbc;
    BL sa, sb, sg, sx;
    float nzx, nzy;
    bool fast;
    float2 va0, va1, vb0, vb1, vg0, vg1;
    float4 xm, x0, x1, x2;
    float fav, fpv, fnv, fsv, Jx, Jy;
};

__device__ __forceinline__ void task_setup(Task& T, int rank, const LevelPtrs& P,
                                           int lvl, int c, int W, int H, float inv_s,
                                           const float* __restrict__ ma,
                                           const float* __restrict__ mb,
                                           const float* __restrict__ ng) {
    const int b = rank >> 11;
    const int q = rank;
    const int HW = H * W;
    T.fac = P.fa[lvl] + (size_t)(b * 32 + c) * HW;
    T.fbc = P.fb[lvl] + (size_t)(b * 32 + c) * HW;
    const float* noise = P.nz[lvl];
    const int p2 = q * 2;
    T.nzx = noise[p2]; T.nzy = noise[p2 + 1];
    const float pax = ma[p2] * inv_s, pay = ma[p2 + 1] * inv_s;
    const float pbx = mb[p2] * inv_s, pby = mb[p2 + 1] * inv_s;
    const float pnx = ng[p2] * inv_s, pny = ng[p2 + 1] * inv_s;
    const float xsx = T.nzx + pbx, xsy = T.nzy + pby;
    T.sa = bl_setup2(pax, pay, W, H);
    T.sb = bl_setup2(pbx, pby, W, H);
    T.sg = bl_setup2(pnx, pny, W, H);
    T.sx = bl_setup2(xsx, xsy, W, H);
    T.fast = (T.sx.x0 >= 1) & (T.sx.x0 <= W - 3) & (T.sx.y0 >= 1) & (T.sx.y0 <= H - 3);
}

__device__ __forceinline__ void task_issue(Task& T, int W, int H) {
    T.va0 = load2u(T.fac + T.sa.y0 * W + T.sa.x0);
    T.va1 = load2u(T.fac + T.sa.y1 * W + T.sa.x0);
    T.vb0 = load2u(T.fbc + T.sb.y0 * W + T.sb.x0);
    T.vb1 = load2u(T.fbc + T.sb.y1 * W + T.sb.x0);
    T.vg0 = load2u(T.fbc + T.sg.y0 * W + T.sg.x0);
    T.vg1 = load2u(T.fbc + T.sg.y1 * W + T.sg.x0);
    int bx0 = min(max(T.sx.x0 - 1, 0), W - 4);
    int by0 = min(max(T.sx.y0 - 1, 0), H - 4);
    const float* xbp = T.fbc + by0 * W + bx0;
    T.xm = load4u(xbp);
    T.x0 = load4u(xbp + W);
    T.x1 = load4u(xbp + 2 * W);
    T.x2 = load4u(xbp + 3 * W);
}

__device__ __forceinline__ void task_consume(Task& T, int W, int H) {
    {
        float t0 = T.va0.x + T.sa.wx * (T.va0.y - T.va0.x);
        float t1 = T.va1.x + T.sa.wx * (T.va1.y - T.va1.x);
        T.fav = t0 + T.sa.wy * (t1 - t0);
    }
    {
        float t0 = T.vb0.x + T.sb.wx * (T.vb0.y - T.vb0.x);
        float t1 = T.vb1.x + T.sb.wx * (T.vb1.y - T.vb1.x);
        T.fpv = t0 + T.sb.wy * (t1 - t0);
    }
    {
        float t0 = T.vg0.x + T.sg.wx * (T.vg0.y - T.vg0.x);
        float t1 = T.vg1.x + T.sg.wx * (T.vg1.y - T.vg1.x);
        T.fnv = t0 + T.sg.wy * (t1 - t0);
    }
    if (T.fast) {
        float wx = T.sx.wx, wy = T.sx.wy;
        float t0 = T.x0.y + wx * (T.x0.z - T.x0.y);
        float t1 = T.x1.y + wx * (T.x1.z - T.x1.y);
        T.fsv = t0 + wy * (t1 - t0);
        float gx00 = T.x0.z - T.x0.x, gx01 = T.x0.w - T.x0.y;
        float gx10 = T.x1.z - T.x1.x, gx11 = T.x1.w - T.x1.y;
        float gy00 = T.x1.y - T.xm.y, gy01 = T.x1.z - T.xm.z;
        float gy10 = T.x2.y - T.x0.y, gy11 = T.x2.z - T.x0.z;
        float g0 = gx00 + wx * (gx01 - gx00);
        float g1 = gx10 + wx * (gx11 - gx10);
        T.Jx = 0.5f * (g0 + wy * (g1 - g0));
        float h0 = gy00 + wx * (gy01 - gy00);
        float h1 = gy10 + wx * (gy11 - gy10);
        T.Jy = 0.5f * (h0 + wy * (h1 - h0));
    } else {
        T.fsv = bl_eval_slow(T.fbc, W, T.sx);
        j_eval_slow(T.fbc, W, H, T.sx, T.Jx, T.Jy);
    }
}

__device__ __forceinline__ void task_reduce(const Task& T, int c, float* red0,
                                            float* red1, float* red2, int slot2) {
    float r = T.fsv - T.fav;
    float a  = warp32_sum(T.Jx * T.Jx);
    float dd = warp32_sum(T.Jy * T.Jy);
    float bb = warp32_sum(T.Jx * T.Jy);
    float bx = warp32_sum(T.Jx * r);
    float by = warp32_sum(T.Jy * r);
    float dfp = T.fav - T.fpv, dfn = T.fav - T.fnv;
    float sp = warp32_sum(dfp * dfp);
    float sn = warp32_sum(dfn * dfn);
    if (c == 0) {
        a += 1e-9f; dd += 1e-9f;
        float det = a * dd - bb * bb;
        float ix = (dd * bx - bb * by) / det;
        float iy = (a * by - bb * bx) / det;
        float dux = ix - T.nzx;
        float duy = iy - T.nzy;
        float qv = a * dux * dux + 2.0f * bb * dux * duy + dd * duy * duy;
        red0[slot2] = fmaxf(sqrtf(sp) - sqrtf(sn) + 1.0f, 0.0f);
        red1[slot2] = qv;
        red2[slot2] = logf(det);
    }
}

__global__ __launch_bounds__(256) void gn_fallback_kernel(
    LevelPtrs P, const float* __restrict__ ma, const float* __restrict__ mb,
    const float* __restrict__ ng, float* __restrict__ blk_out) {
    const int tid = threadIdx.x;
    const int c = tid & 31;
    const int slot = tid >> 5;
    const int lvl = slot >> 1;
    const int po = slot & 1;
    const int bid = blockIdx.x;
    const int base = bid * 4;
    const int H = 64 << lvl;
    const int W = H;
    const float inv_s = 0.0625f * (float)(1 << lvl);

    Task T0, T1;
    task_setup(T0, base + po,     P, lvl, c, W, H, inv_s, ma, mb, ng);
    task_setup(T1, base + 2 + po, P, lvl, c, W, H, inv_s, ma, mb, ng);
    task_issue(T0, W, H);
    task_issue(T1, W, H);
    task_consume(T0, W, H);
    task_consume(T1, W, H);

    __shared__ float red[3][16];
    task_reduce(T0, c, red[0], red[1], red[2], slot * 2 + 0);
    task_reduce(T1, c, red[0], red[1], red[2], slot * 2 + 1);
    __syncthreads();
    if (tid == 0) {
        float t = 0.0f, qq = 0.0f, l = 0.0f;
        #pragma unroll
        for (int i = 0; i < 16; ++i) { t += red[0][i]; qq += red[1][i]; l += red[2][i]; }
        blk_out[bid * 3 + 0] = t;
        blk_out[bid * 3 + 1] = qq;
        blk_out[bid * 3 + 2] = l;
    }
}

extern "C" void kernel_launch(void* const* d_in, const int* in_sizes, int n_in,
                              void* d_out, int out_size, void* d_ws, size_t ws_size,
                              hipStream_t stream) {
    // setup_inputs() dict order: fa0,fb0,noise0, ..., ma,mb,neg,epoch.
    const bool dict_order = (in_sizes[1] == in_sizes[0]);
    LevelPtrs P;
    for (int i = 0; i < 4; ++i) {
        if (dict_order) {
            P.fa[i] = (const float*)d_in[3 * i + 0];
            P.fb[i] = (const float*)d_in[3 * i + 1];
            P.nz[i] = (const float*)d_in[3 * i + 2];
        } else {
            P.fa[i] = (const float*)d_in[i];
            P.fb[i] = (const float*)d_in[4 + i];
            P.nz[i] = (const float*)d_in[8 + i];
        }
    }
    const float* ma = (const float*)d_in[12];
    const float* mb = (const float*)d_in[13];
    const float* ng = (const float*)d_in[14];

    float* ws = (float*)d_ws;
    // ws layout (floats):
    //   [0, 1536)                 : block partials (512 blocks x 3)
    //   [1536, 1536+24576)        : perms (3 x 8192 ints)
    //   [26112, 26112+1048576)    : ft  (4 lvls x 8192 pts x 32 ch)
    //   [.., +1048576)            : fn
    const size_t FT_OFF = 26112;
    const size_t FN_OFF = FT_OFF + 4 * 8192 * 32;
    const size_t NEED = (FN_OFF + 4 * 8192 * 32) * 4;

    if (ws_size >= NEED) {
        float* partials = ws;
        int* perm = (int*)(ws + 1536);
        float* ft = ws + FT_OFF;
        float* fn = ws + FN_OFF;
        sort3_kernel<<<12, 1024, 0, stream>>>(ma, mb, ng, perm);
        gather_pass_kernel<<<1024, 256, 0, stream>>>(P, ma, ng, perm, ft, fn);
        gn_main_kernel<<<512, 256, 0, stream>>>(P, mb, perm + 8192, ft, fn, partials);
        gn_final_kernel<<<1, 256, 0, stream>>>(partials, 512, (float*)d_out);
    } else {
        // Fallback: fused kernel (no sort, no intermediates).
        float* partials = ws;                // 2048 blocks x 3 floats = 24 KB
        gn_fallback_kernel<<<2048, 256, 0, stream>>>(P, ma, mb, ng, partials);
        gn_final_kernel<<<1, 256, 0, stream>>>(partials, 2048, (float*)d_out);
    }
}